// Round 12
// baseline (271.194 us; speedup 1.0000x reference)
//
#include <hip/hip_runtime.h>
#include <hip/hip_bf16.h>

#define N 8192
#define D 128
#define WEIGHT 0.01f
#define NTILES 64            // N / 128
#define NBLK 2080            // NTILES*(NTILES+1)/2
#define NTAIL 64             // tail bands, handled by the last 64 finishers

typedef __bf16 bf16x8 __attribute__((ext_vector_type(8)));
typedef float floatx4 __attribute__((ext_vector_type(4)));

// ---- Kernel 1: L2-normalize rows (fp32) -> bf16, stored XOR-SWIZZLED
//      (16B chunk c of row r at position c ^ (r & 15)); zero out[0] and sync cells.
__global__ __launch_bounds__(256) void k_norm(const float* __restrict__ x,
                                              __hip_bfloat16* __restrict__ fb,
                                              float* __restrict__ out,
                                              unsigned* __restrict__ sync) {
    int gid = blockIdx.x * 256 + threadIdx.x;   // 512 blocks
    if (gid == 0) { out[0] = 0.0f; sync[0] = 0u; sync[32] = 0u; }
    int row = gid >> 4;                          // 16 threads per row
    int c   = gid & 15;
    const float4* xr = (const float4*)(x + (size_t)row * D + c * 8);
    float4 f0 = xr[0], f1 = xr[1];
    float s = f0.x * f0.x + f0.y * f0.y + f0.z * f0.z + f0.w * f0.w
            + f1.x * f1.x + f1.y * f1.y + f1.z * f1.z + f1.w * f1.w;
    s += __shfl_xor(s, 1, 64);
    s += __shfl_xor(s, 2, 64);
    s += __shfl_xor(s, 4, 64);
    s += __shfl_xor(s, 8, 64);                   // 16-lane group = one row
    float inv = 1.0f / fmaxf(sqrtf(s), 1e-12f);
    union { __hip_bfloat16 h[8]; uint4 u; } pk;
    pk.h[0] = __float2bfloat16(f0.x * inv);
    pk.h[1] = __float2bfloat16(f0.y * inv);
    pk.h[2] = __float2bfloat16(f0.z * inv);
    pk.h[3] = __float2bfloat16(f0.w * inv);
    pk.h[4] = __float2bfloat16(f1.x * inv);
    pk.h[5] = __float2bfloat16(f1.y * inv);
    pk.h[6] = __float2bfloat16(f1.z * inv);
    pk.h[7] = __float2bfloat16(f1.w * inv);
    ((uint4*)fb)[(size_t)row * 16 + (c ^ (row & 15))] = pk.u;
}

// ---- Kernel 2: gram tiles (R6/R11 body, unchanged) + fused tail via
//      finish-ticket: the last 64 finishers each reduce one band and
//      atomicAdd into out[0]; ticket 2079 release-publishes the flag.
__global__ __launch_bounds__(256, 2) void k_gram(const __hip_bfloat16* __restrict__ fb,
                                                 float* __restrict__ Prow,
                                                 float* __restrict__ Pcol,
                                                 float* __restrict__ p,
                                                 float* __restrict__ ep,
                                                 unsigned* __restrict__ sync,
                                                 float* __restrict__ out) {
    int b = blockIdx.x;                  // 0 .. 2079
    int bi = (int)((2.0 * NTILES + 1.0 - sqrt((2.0 * NTILES + 1.0) * (2.0 * NTILES + 1.0) - 8.0 * (double)b)) * 0.5);
    while (bi * NTILES - bi * (bi - 1) / 2 > b) --bi;
    while ((bi + 1) * NTILES - (bi + 1) * bi / 2 <= b) ++bi;
    int bj = bi + (b - (bi * NTILES - bi * (bi - 1) / 2));

    __shared__ uint4 Ab[2048];           // pre-swizzled tile rows (32 KB)
    __shared__ uint4 Bb[2048];
    __shared__ float PR[2][128];
    __shared__ float PC[2][128];
    __shared__ unsigned ticket_sh;

    const int t = threadIdx.x;
    const int lane = t & 63;
    const int wid  = t >> 6;             // 4 waves, 2x2
    const int wrow = wid >> 1, wcol = wid & 1;
    const int col0 = lane & 15;
    const int quad = lane >> 4;
    const int rbase = bi * 128, cbase = bj * 128;

    const uint4* gA = (const uint4*)fb + (size_t)rbase * 16;
    const uint4* gB = (const uint4*)fb + (size_t)cbase * 16;
    #pragma unroll
    for (int i = 0; i < 8; ++i) {
        int ca = wid * 512 + i * 64;
        __builtin_amdgcn_global_load_lds(
            (const __attribute__((address_space(1))) void*)(gA + ca + lane),
            (__attribute__((address_space(3))) void*)&Ab[ca], 16, 0, 0);
        __builtin_amdgcn_global_load_lds(
            (const __attribute__((address_space(1))) void*)(gB + ca + lane),
            (__attribute__((address_space(3))) void*)&Bb[ca], 16, 0, 0);
    }
    __syncthreads();

    floatx4 acc[4][4];
    #pragma unroll
    for (int a = 0; a < 4; ++a)
        #pragma unroll
        for (int c = 0; c < 4; ++c)
            acc[a][c] = (floatx4){0.0f, 0.0f, 0.0f, 0.0f};

    #pragma unroll
    for (int ks = 0; ks < 4; ++ks) {
        bf16x8 af[4], bfr[4];
        int j = ks * 4 + quad;
        int jsw = j ^ col0;
        #pragma unroll
        for (int mt = 0; mt < 4; ++mt) {
            int rl = wrow * 64 + mt * 16 + col0;
            af[mt] = *(const bf16x8*)&Ab[rl * 16 + jsw];
        }
        #pragma unroll
        for (int nt = 0; nt < 4; ++nt) {
            int cl = wcol * 64 + nt * 16 + col0;
            bfr[nt] = *(const bf16x8*)&Bb[cl * 16 + jsw];
        }
        #pragma unroll
        for (int mt = 0; mt < 4; ++mt)
            #pragma unroll
            for (int nt = 0; nt < 4; ++nt)
                acc[mt][nt] = __builtin_amdgcn_mfma_f32_16x16x32_bf16(af[mt], bfr[nt], acc[mt][nt], 0, 0, 0);
    }

    float v[16];
    float colpart[4];
    #pragma unroll
    for (int m = 0; m < 16; ++m) v[m] = 0.0f;
    #pragma unroll
    for (int m = 0; m < 4; ++m) colpart[m] = 0.0f;

    if (bj > bi + 1) {
        #pragma unroll
        for (int mt = 0; mt < 4; ++mt)
            #pragma unroll
            for (int nt = 0; nt < 4; ++nt)
                #pragma unroll
                for (int reg = 0; reg < 4; ++reg) {
                    float e = __expf(acc[mt][nt][reg]);
                    v[mt * 4 + reg] += e;
                    colpart[nt] += e;
                }
    } else {
        #pragma unroll
        for (int mt = 0; mt < 4; ++mt)
            #pragma unroll
            for (int nt = 0; nt < 4; ++nt)
                #pragma unroll
                for (int reg = 0; reg < 4; ++reg) {
                    int r = rbase + wrow * 64 + mt * 16 + quad * 4 + reg;
                    int c = cbase + wcol * 64 + nt * 16 + col0;
                    float s0 = acc[mt][nt][reg];
                    float e = __expf(s0);
                    if (c == r + 1) { p[r] = s0; ep[r] = e; }
                    e = (c > r) ? e : 0.0f;
                    v[mt * 4 + reg] += e;
                    colpart[nt] += e;
                }
    }

    // Row sums: value-halving butterfly (15 shuffles, all lanes distinct rows).
    float v8[8];
    #pragma unroll
    for (int k = 0; k < 8; ++k) {
        float a = v[2 * k], bb = v[2 * k + 1];
        float give = (lane & 1) ? a : bb;
        float keep = (lane & 1) ? bb : a;
        v8[k] = keep + __shfl_xor(give, 1, 64);
    }
    float v4[4];
    #pragma unroll
    for (int k = 0; k < 4; ++k) {
        float a = v8[2 * k], bb = v8[2 * k + 1];
        float give = (lane & 2) ? a : bb;
        float keep = (lane & 2) ? bb : a;
        v4[k] = keep + __shfl_xor(give, 2, 64);
    }
    float v2[2];
    #pragma unroll
    for (int k = 0; k < 2; ++k) {
        float a = v4[2 * k], bb = v4[2 * k + 1];
        float give = (lane & 4) ? a : bb;
        float keep = (lane & 4) ? bb : a;
        v2[k] = keep + __shfl_xor(give, 4, 64);
    }
    {
        float a = v2[0], bb = v2[1];
        float give = (lane & 8) ? a : bb;
        float keep = (lane & 8) ? bb : a;
        float v1 = keep + __shfl_xor(give, 8, 64);
        int rowl = wrow * 64 + (col0 >> 2) * 16 + quad * 4 + (col0 & 3);
        PR[wcol][rowl] = v1;
    }
    {
        float c2[2];
        #pragma unroll
        for (int k = 0; k < 2; ++k) {
            float a = colpart[2 * k];
            float bb = colpart[2 * k + 1];
            float give = (lane & 16) ? a : bb;
            float keep = (lane & 16) ? bb : a;
            c2[k] = keep + __shfl_xor(give, 16, 64);
        }
        float a = c2[0], bb = c2[1];
        float give = (lane & 32) ? a : bb;
        float keep = (lane & 32) ? bb : a;
        float cv = keep + __shfl_xor(give, 32, 64);
        PC[wrow][wcol * 64 + lane] = cv;
    }
    __syncthreads();

    if (t < 128) {
        Prow[(size_t)b * 128 + t] = PR[0][t] + PR[1][t];
    } else {
        int c = t - 128;
        Pcol[(size_t)b * 128 + c] = PC[0][c] + PC[1][c];
    }

    // ---- Finish ticket: last NTAIL finishers run the tail (one band each).
    __threadfence();                     // all threads: make partial stores visible
    __syncthreads();
    if (t == 0)
        ticket_sh = __hip_atomic_fetch_add(&sync[0], 1u, __ATOMIC_ACQ_REL, __HIP_MEMORY_SCOPE_AGENT);
    __syncthreads();
    unsigned ticket = ticket_sh;
    if (ticket < NBLK - NTAIL) return;   // not a tail block

    if (ticket == NBLK - 1) {            // all 2080 stores complete & visible
        if (t == 0)
            __hip_atomic_store(&sync[32], 1u, __ATOMIC_RELEASE, __HIP_MEMORY_SCOPE_AGENT);
    } else {
        if (t == 0)
            while (__hip_atomic_load(&sync[32], __ATOMIC_ACQUIRE, __HIP_MEMORY_SCOPE_AGENT) == 0u)
                __builtin_amdgcn_s_sleep(4);
        __syncthreads();
    }

    // ---- Tail: band = ticket - (NBLK - NTAIL); Ush/Lsh reuse PR LDS.
    {
        int band = (int)ticket - (NBLK - NTAIL);
        if (t < 128) {
            int baseU = band * NTILES - band * (band - 1) / 2;
            float s = 0.0f;
            for (int bjj = band; bjj < NTILES; ++bjj)
                s += Prow[(size_t)(baseU + bjj - band) * 128 + t];
            PR[0][t] = s;                // Ush
        } else {
            int c = band * 128 + (t - 128) + 1;
            float s = 0.0f;
            if (c < N) {
                int bc = c >> 7;
                for (int bii = 0; bii <= bc; ++bii)
                    s += Pcol[(size_t)(bii * NTILES - bii * (bii - 1) / 2 + (bc - bii)) * 128 + (c & 127)];
            }
            PR[1][t - 128] = s;          // Lsh
        }
        __syncthreads();
        float term = 0.0f;
        if (t < 128) {
            int r = band * 128 + t;
            if (r < N - 1)
                term = __logf(PR[0][t] + PR[1][t] - ep[r]) - p[r];
        }
        #pragma unroll
        for (int m = 1; m < 64; m <<= 1) term += __shfl_xor(term, m, 64);
        if (lane == 0) PC[0][wid] = term;
        __syncthreads();
        if (t == 0) {
            float part = PC[0][0] + PC[0][1] + PC[0][2] + PC[0][3];
            atomicAdd(out, -WEIGHT * part / (float)N);
        }
    }
}

extern "C" void kernel_launch(void* const* d_in, const int* in_sizes, int n_in,
                              void* d_out, int out_size, void* d_ws, size_t ws_size,
                              hipStream_t stream) {
    const float* x = (const float*)d_in[0];
    float* out = (float*)d_out;
    char* ws = (char*)d_ws;
    __hip_bfloat16* fb = (__hip_bfloat16*)ws;                  // N*D*2 = 2 MB
    float* p    = (float*)(ws + (size_t)N * D * 2);            // N floats
    float* ep   = p + N;
    unsigned* sync = (unsigned*)(ep + N);                      // isolated cells: [0]=cnt, [32]=flag
    float* Prow = (float*)(sync + 64);                         // NBLK*128 floats
    float* Pcol = Prow + (size_t)NBLK * 128;

    hipLaunchKernelGGL(k_norm, dim3(512),  dim3(256), 0, stream, x, fb, out, sync);
    hipLaunchKernelGGL(k_gram, dim3(NBLK), dim3(256), 0, stream, fb, Prow, Pcol, p, ep, sync, out);
}

// Round 13
// 91.586 us; speedup vs baseline: 2.9611x; 2.9611x over previous
//
#include <hip/hip_runtime.h>
#include <hip/hip_bf16.h>
#include <hip/hip_fp8.h>

#define N 8192
#define D 128
#define WEIGHT 0.01f
#define NTILES 64            // N / 128
#define NBLK 2080            // NTILES*(NTILES+1)/2

typedef float floatx4 __attribute__((ext_vector_type(4)));

// ---- Kernel 1: L2-normalize rows (fp32) -> fp8 e4m3, stored XOR-SWIZZLED:
//      16B chunk cc of row r lands at chunk position cc ^ (r & 7) (8 chunks/row),
//      so k_gram's linear global_load_lds copy produces a low-conflict LDS layout.
__global__ __launch_bounds__(256) void k_norm(const float* __restrict__ x,
                                              unsigned char* __restrict__ fb8,
                                              float* __restrict__ out) {
    int gid = blockIdx.x * 256 + threadIdx.x;   // 512 blocks
    if (gid == 0) out[0] = 0.0f;
    int row = gid >> 4;                          // 16 threads per row
    int c   = gid & 15;                          // 8 floats -> 8 fp8 bytes per thread
    const float4* xr = (const float4*)(x + (size_t)row * D + c * 8);
    float4 f0 = xr[0], f1 = xr[1];
    float s = f0.x * f0.x + f0.y * f0.y + f0.z * f0.z + f0.w * f0.w
            + f1.x * f1.x + f1.y * f1.y + f1.z * f1.z + f1.w * f1.w;
    s += __shfl_xor(s, 1, 64);
    s += __shfl_xor(s, 2, 64);
    s += __shfl_xor(s, 4, 64);
    s += __shfl_xor(s, 8, 64);                   // 16-lane group = one row
    float inv = 1.0f / fmaxf(sqrtf(s), 1e-12f);
    union { unsigned char b[8]; uint2 u; } pk;
    pk.b[0] = __hip_fp8_e4m3(f0.x * inv).__x;
    pk.b[1] = __hip_fp8_e4m3(f0.y * inv).__x;
    pk.b[2] = __hip_fp8_e4m3(f0.z * inv).__x;
    pk.b[3] = __hip_fp8_e4m3(f0.w * inv).__x;
    pk.b[4] = __hip_fp8_e4m3(f1.x * inv).__x;
    pk.b[5] = __hip_fp8_e4m3(f1.y * inv).__x;
    pk.b[6] = __hip_fp8_e4m3(f1.z * inv).__x;
    pk.b[7] = __hip_fp8_e4m3(f1.w * inv).__x;
    int cc = c >> 1, h = c & 1;                  // 16B chunk + 8B half
    ((uint2*)fb8)[(size_t)row * 16 + (((cc ^ (row & 7)) << 1) | h)] = pk.u;
}

// ---- Kernel 2: upper-triangle 128x128 tiles of sim = F F^T, fp8 e4m3 MFMA.
//      R11 structure; staging 16 KB/tile (half of bf16), LDS 34 KB ->
//      4 blocks/CU (vs 2) = 4-deep phase diversity. 4 waves (2x2), 64x64/wave.
__global__ __launch_bounds__(256, 4) void k_gram(const unsigned char* __restrict__ fb8,
                                                 float* __restrict__ Prow,
                                                 float* __restrict__ Pcol,
                                                 float* __restrict__ p,
                                                 float* __restrict__ ep) {
    int b = blockIdx.x;                  // 0 .. 2079
    int bi = (int)((2.0 * NTILES + 1.0 - sqrt((2.0 * NTILES + 1.0) * (2.0 * NTILES + 1.0) - 8.0 * (double)b)) * 0.5);
    while (bi * NTILES - bi * (bi - 1) / 2 > b) --bi;
    while ((bi + 1) * NTILES - (bi + 1) * bi / 2 <= b) ++bi;
    int bj = bi + (b - (bi * NTILES - bi * (bi - 1) / 2));

    __shared__ uint4 Ab[1024];           // 128 rows x 128 fp8, pre-swizzled (16 KB)
    __shared__ uint4 Bb[1024];
    __shared__ float PR[2][128];
    __shared__ float PC[2][128];

    const int t = threadIdx.x;
    const int lane = t & 63;
    const int wid  = t >> 6;             // 4 waves, 2x2
    const int wrow = wid >> 1, wcol = wid & 1;
    const int col0 = lane & 15;
    const int quad = lane >> 4;
    const int rbase = bi * 128, cbase = bj * 128;

    const uint4* gA = (const uint4*)fb8 + (size_t)rbase * 8;   // 8 chunks/row
    const uint4* gB = (const uint4*)fb8 + (size_t)cbase * 8;
    #pragma unroll
    for (int i = 0; i < 4; ++i) {
        int ca = wid * 256 + i * 64;     // wave-uniform chunk base; lane adds *16B
        __builtin_amdgcn_global_load_lds(
            (const __attribute__((address_space(1))) void*)(gA + ca + lane),
            (__attribute__((address_space(3))) void*)&Ab[ca], 16, 0, 0);
        __builtin_amdgcn_global_load_lds(
            (const __attribute__((address_space(1))) void*)(gB + ca + lane),
            (__attribute__((address_space(3))) void*)&Bb[ca], 16, 0, 0);
    }
    __syncthreads();

    floatx4 acc[4][4];
    #pragma unroll
    for (int a = 0; a < 4; ++a)
        #pragma unroll
        for (int c = 0; c < 4; ++c)
            acc[a][c] = (floatx4){0.0f, 0.0f, 0.0f, 0.0f};

    const long* A8 = (const long*)Ab;    // row = 16 x 8B units
    const long* B8 = (const long*)Bb;
    const int swz = (col0 & 7);
    #pragma unroll
    for (int ks = 0; ks < 4; ++ks) {     // K = 128 = 4 x 32
        long af[4], bfr[4];
        int cc = ks * 2 + (quad >> 1);   // 16B chunk holding k = ks*32 + quad*8
        int off = quad & 1;              // 8B half
        int base8 = ((cc ^ swz) << 1) | off;
        #pragma unroll
        for (int mt = 0; mt < 4; ++mt) { // A[m=lane&15][k=quad*8+j]
            int rl = wrow * 64 + mt * 16 + col0;
            af[mt] = A8[rl * 16 + base8];
        }
        #pragma unroll
        for (int nt = 0; nt < 4; ++nt) { // B^T[n=lane&15][k]
            int cl = wcol * 64 + nt * 16 + col0;
            bfr[nt] = B8[cl * 16 + base8];
        }
        #pragma unroll
        for (int mt = 0; mt < 4; ++mt)
            #pragma unroll
            for (int nt = 0; nt < 4; ++nt)
                acc[mt][nt] = __builtin_amdgcn_mfma_f32_16x16x32_fp8_fp8(af[mt], bfr[nt], acc[mt][nt], 0, 0, 0);
    }

    float v[16];
    float colpart[4];
    #pragma unroll
    for (int m = 0; m < 16; ++m) v[m] = 0.0f;
    #pragma unroll
    for (int m = 0; m < 4; ++m) colpart[m] = 0.0f;

    if (bj > bi + 1) {
        #pragma unroll
        for (int mt = 0; mt < 4; ++mt)
            #pragma unroll
            for (int nt = 0; nt < 4; ++nt)
                #pragma unroll
                for (int reg = 0; reg < 4; ++reg) {
                    float e = __expf(acc[mt][nt][reg]);
                    v[mt * 4 + reg] += e;
                    colpart[nt] += e;
                }
    } else {
        #pragma unroll
        for (int mt = 0; mt < 4; ++mt)
            #pragma unroll
            for (int nt = 0; nt < 4; ++nt)
                #pragma unroll
                for (int reg = 0; reg < 4; ++reg) {
                    int r = rbase + wrow * 64 + mt * 16 + quad * 4 + reg;
                    int c = cbase + wcol * 64 + nt * 16 + col0;
                    float s0 = acc[mt][nt][reg];
                    float e = __expf(s0);
                    if (c == r + 1) { p[r] = s0; ep[r] = e; }
                    e = (c > r) ? e : 0.0f;
                    v[mt * 4 + reg] += e;
                    colpart[nt] += e;
                }
    }

    // Row sums: value-halving butterfly (15 shuffles, all lanes distinct rows).
    float v8[8];
    #pragma unroll
    for (int k = 0; k < 8; ++k) {
        float a = v[2 * k], bb = v[2 * k + 1];
        float give = (lane & 1) ? a : bb;
        float keep = (lane & 1) ? bb : a;
        v8[k] = keep + __shfl_xor(give, 1, 64);
    }
    float v4[4];
    #pragma unroll
    for (int k = 0; k < 4; ++k) {
        float a = v8[2 * k], bb = v8[2 * k + 1];
        float give = (lane & 2) ? a : bb;
        float keep = (lane & 2) ? bb : a;
        v4[k] = keep + __shfl_xor(give, 2, 64);
    }
    float v2[2];
    #pragma unroll
    for (int k = 0; k < 2; ++k) {
        float a = v4[2 * k], bb = v4[2 * k + 1];
        float give = (lane & 4) ? a : bb;
        float keep = (lane & 4) ? bb : a;
        v2[k] = keep + __shfl_xor(give, 4, 64);
    }
    {
        float a = v2[0], bb = v2[1];
        float give = (lane & 8) ? a : bb;
        float keep = (lane & 8) ? bb : a;
        float v1 = keep + __shfl_xor(give, 8, 64);
        int rowl = wrow * 64 + (col0 >> 2) * 16 + quad * 4 + (col0 & 3);
        PR[wcol][rowl] = v1;
    }
    {
        float c2[2];
        #pragma unroll
        for (int k = 0; k < 2; ++k) {
            float a = colpart[2 * k];
            float bb = colpart[2 * k + 1];
            float give = (lane & 16) ? a : bb;
            float keep = (lane & 16) ? bb : a;
            c2[k] = keep + __shfl_xor(give, 16, 64);
        }
        float a = c2[0], bb = c2[1];
        float give = (lane & 32) ? a : bb;
        float keep = (lane & 32) ? bb : a;
        float cv = keep + __shfl_xor(give, 32, 64);
        PC[wrow][wcol * 64 + lane] = cv;
    }
    __syncthreads();

    if (t < 128) {
        Prow[(size_t)b * 128 + t] = PR[0][t] + PR[1][t];
    } else {
        int c = t - 128;
        Pcol[(size_t)b * 128 + c] = PC[0][c] + PC[1][c];
    }
}

// ---- Kernel 3 (merged reduce+final, R11): per band of 128 rows, U and L into
//      LDS, log terms, block-reduce, one scaled atomicAdd into out[0].
__global__ __launch_bounds__(256) void k_tail(const float* __restrict__ Prow,
                                              const float* __restrict__ Pcol,
                                              const float* __restrict__ p,
                                              const float* __restrict__ ep,
                                              float* __restrict__ out) {
    __shared__ float Ush[128];
    __shared__ float Lsh[128];           // Lsh[i] = L[band*128 + i + 1]
    __shared__ float sw[4];
    int band = blockIdx.x;               // 0..63
    int t = threadIdx.x;
    if (t < 128) {
        int baseU = band * NTILES - band * (band - 1) / 2;
        float s = 0.0f;
        for (int bj = band; bj < NTILES; ++bj)
            s += Prow[(size_t)(baseU + bj - band) * 128 + t];
        Ush[t] = s;
    } else {
        int c = band * 128 + (t - 128) + 1;      // base+1 .. base+128
        float s = 0.0f;
        if (c < N) {
            int bc = c >> 7;
            for (int bi = 0; bi <= bc; ++bi)
                s += Pcol[(size_t)(bi * NTILES - bi * (bi - 1) / 2 + (bc - bi)) * 128 + (c & 127)];
        }
        Lsh[t - 128] = s;
    }
    __syncthreads();
    float term = 0.0f;
    if (t < 128) {
        int r = band * 128 + t;
        if (r < N - 1)
            term = __logf(Ush[t] + Lsh[t] - ep[r]) - p[r];
    }
    #pragma unroll
    for (int m = 1; m < 64; m <<= 1) term += __shfl_xor(term, m, 64);
    int lane = t & 63, wd = t >> 6;
    if (lane == 0) sw[wd] = term;
    __syncthreads();
    if (t == 0) {
        float part = sw[0] + sw[1] + sw[2] + sw[3];
        atomicAdd(out, -WEIGHT * part / (float)N);
    }
}

extern "C" void kernel_launch(void* const* d_in, const int* in_sizes, int n_in,
                              void* d_out, int out_size, void* d_ws, size_t ws_size,
                              hipStream_t stream) {
    const float* x = (const float*)d_in[0];
    float* out = (float*)d_out;
    char* ws = (char*)d_ws;
    unsigned char* fb8 = (unsigned char*)ws;                   // N*D = 1 MB
    float* p    = (float*)(ws + (size_t)N * D);                // N floats
    float* ep   = p + N;
    float* Prow = ep + N;                                      // NBLK*128 floats
    float* Pcol = Prow + (size_t)NBLK * 128;

    hipLaunchKernelGGL(k_norm, dim3(512),  dim3(256), 0, stream, x, fb8, out);
    hipLaunchKernelGGL(k_gram, dim3(NBLK), dim3(256), 0, stream, fb8, Prow, Pcol, p, ep);
    hipLaunchKernelGGL(k_tail, dim3(64),   dim3(256), 0, stream, Prow, Pcol, p, ep, out);
}